// Round 5
// baseline (703.150 us; speedup 1.0000x reference)
//
#include <hip/hip_runtime.h>

typedef _Float16 f16;
typedef _Float16 f16x8 __attribute__((ext_vector_type(8)));
typedef _Float16 f16x4 __attribute__((ext_vector_type(4)));
typedef float    f32x4 __attribute__((ext_vector_type(4)));
typedef unsigned int u32;
typedef u32 u32x2 __attribute__((ext_vector_type(2)));
typedef u32 u32x4 __attribute__((ext_vector_type(4)));
typedef unsigned short ush;

#define CC 256
#define NN 4096
#define BB 4
#define RS 264          // row stride (halves) for K/Q tiles
#define RSV 40          // row stride (halves) for V tile
#define RSC 17          // row stride (f32) for combine buffer

union Frag8 { u32x4 u4; f16x8 f; };
union Frag4 { u32x2 u2; f16x4 f; };

static __device__ __forceinline__ u32 pkrtz(float a, float b) {
  auto t = __builtin_amdgcn_cvt_pkrtz(a, b);
  return __builtin_bit_cast(u32, t);
}
static __device__ __forceinline__ float h2fu(u32 u) {
  f16 h = __builtin_bit_cast(f16, (ush)(u & 0xffffu));
  return (float)h;
}

#define MFMA32(A, B, C) __builtin_amdgcn_mfma_f32_16x16x32_f16((A), (B), (C), 0, 0, 0)
#define MFMA16(A, B, C) __builtin_amdgcn_mfma_f32_16x16x16f16((A), (B), (C), 0, 0, 0)

// K1: M[c][cp] = sum_o w1[o,c]*w2[o,cp] ; g[cp] = sum_o b1[o]*w2[o,cp]
__global__ void k_prep(const float* __restrict__ w1, const float* __restrict__ w2,
                       const float* __restrict__ b1, float* __restrict__ M,
                       float* __restrict__ g) {
  const int c  = blockIdx.x;
  const int cp = threadIdx.x;
  float acc = 0.f;
#pragma unroll 8
  for (int o = 0; o < CC; ++o)
    acc += w1[o * CC + c] * w2[o * CC + cp];
  M[c * CC + cp] = acc;
  if (c == 0) {
    float ga = 0.f;
    for (int o = 0; o < CC; ++o)
      ga += b1[o] * w2[o * CC + cp];
    g[cp] = ga;
  }
}

// K2: r2[b*N+j] = sum_c g[c] * x2[b,c,j]
__global__ void k_r2(const float* __restrict__ x2, const float* __restrict__ g,
                     float* __restrict__ r2) {
  const int jg = blockIdx.x * 256 + threadIdx.x;
  const int b  = jg >> 12;
  const int j  = jg & (NN - 1);
  const float* xp = x2 + (((size_t)(b * CC)) << 12) + j;
  float acc = 0.f;
#pragma unroll 8
  for (int c = 0; c < CC; ++c)
    acc += g[c] * xp[(size_t)c << 12];
  r2[jg] = acc;
}

// K-cvt: x2[b][c][j] f32 -> KT_hi/KT_lo[b][j][c] ush ; V tiled [b][jt][c][32] ush
__global__ void k_cvt(const float* __restrict__ x2, ush* __restrict__ kt_hi,
                      ush* __restrict__ kt_lo, ush* __restrict__ vt) {
  __shared__ float Xs[256 * 37];
  const int tid = threadIdx.x;
  const int b   = blockIdx.x >> 7;
  const int jt  = blockIdx.x & 127;
  const int j0  = jt << 5;
  const float* x2b = x2 + ((size_t)b << 20);

  // stage tile [256 c][32 j] f32 (coalesced)
  {
    const int jf = tid & 7, c0 = tid >> 3;
#pragma unroll
    for (int m = 0; m < 8; ++m) {
      int c = c0 + (m << 5);
      float4 v = *(const float4*)(x2b + ((size_t)c << 12) + j0 + (jf << 2));
      *(float4*)(Xs + c * 37 + (jf << 2)) = v;
    }
  }
  __syncthreads();

  // KT rows: thread (j = tid&31, cc = tid>>5) covers c in [32cc, 32cc+32)
  {
    const int j = tid & 31, cc = tid >> 5;
    u32 hi[16], lo[16];
#pragma unroll
    for (int k = 0; k < 32; k += 2) {
      float a  = Xs[(32 * cc + k) * 37 + j];
      float bb = Xs[(32 * cc + k + 1) * 37 + j];
      u32 h = pkrtz(a, bb);
      float ra = a - h2fu(h), rb = bb - h2fu(h >> 16);
      hi[k >> 1] = h;
      lo[k >> 1] = pkrtz(ra, rb);
    }
    size_t rowg = ((size_t)(b << 12) + j0 + j) << 8;   // (b*4096 + j)*256
    ush* ph = kt_hi + rowg + (cc << 5);
    ush* pl = kt_lo + rowg + (cc << 5);
#pragma unroll
    for (int m = 0; m < 4; ++m) {
      u32x4 vh; vh.x = hi[4*m]; vh.y = hi[4*m+1]; vh.z = hi[4*m+2]; vh.w = hi[4*m+3];
      u32x4 vl; vl.x = lo[4*m]; vl.y = lo[4*m+1]; vl.z = lo[4*m+2]; vl.w = lo[4*m+3];
      *(u32x4*)(ph + (m << 3)) = vh;
      *(u32x4*)(pl + (m << 3)) = vl;
    }
  }
  // V tiled: thread c = tid writes 32 halves contiguous
  {
    const int c = tid;
    u32 hv[16];
#pragma unroll
    for (int k = 0; k < 32; k += 2)
      hv[k >> 1] = pkrtz(Xs[c * 37 + k], Xs[c * 37 + k + 1]);
    ush* pv = vt + (((size_t)((b << 7) + jt)) << 13) + (c << 5);
#pragma unroll
    for (int m = 0; m < 4; ++m) {
      u32x4 vv; vv.x = hv[4*m]; vv.y = hv[4*m+1]; vv.z = hv[4*m+2]; vv.w = hv[4*m+3];
      *(u32x4*)(pv + (m << 3)) = vv;
    }
  }
}

// K3 (main): Q-prep + flash attention from preconverted K/V
__launch_bounds__(256, 3)
__global__ void k_attn(const float* __restrict__ x1, const ush* __restrict__ kt_hi,
                       const ush* __restrict__ kt_lo, const ush* __restrict__ vt,
                       const float* __restrict__ M, const float* __restrict__ r2,
                       float* __restrict__ out) {
  extern __shared__ ush lds[];
  ush* Khi = lds;                       // [32][264]h (16896B) | Qhi in prologue
  ush* Klo = lds + 8448;                // [32][264]h           | Qlo in prologue
  ush* V   = lds + 16896;               // [256][40]h (20480B)  | x1f32[256][20] in prologue
  float* x1f = (float*)(lds + 16896);

  const int tid  = threadIdx.x;
  const int lane = tid & 63;
  const int w    = tid >> 6;
  const int p    = w >> 1;     // i-group
  const int h    = w & 1;      // j-group
  const int g    = lane >> 4;
  const int lq   = lane & 15;

  int bid = (int)blockIdx.x;
  bid = (bid & 7) * 64 + (bid >> 3);    // bijective XCD swizzle (512 = 8*64)
  const int b  = bid >> 7;
  const int i0 = (bid & 127) << 5;

  const float* x1b = x1 + ((size_t)b << 20);

  // ---- Q-prep: two i-half passes, direct hi/lo write ----
  for (int ih = 0; ih < 2; ++ih) {
    {
      const int jf = tid & 3, c0 = tid >> 2;
#pragma unroll
      for (int m = 0; m < 4; ++m) {
        int c = c0 + (m << 6);
        float4 v = *(const float4*)(x1b + ((size_t)c << 12) + i0 + (ih << 4) + (jf << 2));
        *(float4*)(x1f + c * 20 + (jf << 2)) = v;
      }
    }
    __syncthreads();
    {
      const int tc = tid & 63, tq = tid >> 6;
      float acc[4][4];
#pragma unroll
      for (int q = 0; q < 4; ++q)
#pragma unroll
        for (int e = 0; e < 4; ++e) acc[q][e] = 0.f;
#pragma unroll 4
      for (int c = 0; c < CC; ++c) {
        float4 mv = *(const float4*)(M + c * CC + (tc << 2));
        float4 xs = *(const float4*)(x1f + c * 20 + (tq << 2));
        float xv[4] = {xs.x, xs.y, xs.z, xs.w};
#pragma unroll
        for (int e = 0; e < 4; ++e) {
          acc[0][e] += mv.x * xv[e];
          acc[1][e] += mv.y * xv[e];
          acc[2][e] += mv.z * xv[e];
          acc[3][e] += mv.w * xv[e];
        }
      }
#pragma unroll
      for (int e = 0; e < 4; ++e) {
        int i = (ih << 4) + (tq << 2) + e;
        u32 h0 = pkrtz(acc[0][e], acc[1][e]);
        u32 h1 = pkrtz(acc[2][e], acc[3][e]);
        float l0 = acc[0][e] - h2fu(h0), l1 = acc[1][e] - h2fu(h0 >> 16);
        float l2 = acc[2][e] - h2fu(h1), l3 = acc[3][e] - h2fu(h1 >> 16);
        u32x2 hw; hw.x = h0; hw.y = h1;
        u32x2 lw; lw.x = pkrtz(l0, l1); lw.y = pkrtz(l2, l3);
        *(u32x2*)(Khi + i * RS + (tc << 2)) = hw;   // Qhi region
        *(u32x2*)(Klo + i * RS + (tc << 2)) = lw;   // Qlo region
      }
    }
    __syncthreads();
  }

  // ---- preload Q B-fragments ----
  Frag8 QBh[8], QBl[8];
  {
    const int qrow = ((p << 4) + lq) * RS;
#pragma unroll
    for (int cs = 0; cs < 8; ++cs) {
      QBh[cs].u4 = *(const u32x4*)(Khi + qrow + (cs << 5) + (g << 3));
      QBl[cs].u4 = *(const u32x4*)(Klo + qrow + (cs << 5) + (g << 3));
    }
  }

  // ---- main flash loop ----
  f32x4 vacc[16];
#pragma unroll
  for (int ct = 0; ct < 16; ++ct) vacc[ct] = (f32x4){0.f, 0.f, 0.f, 0.f};
  float m_run = -3.0e38f, l_run = 0.f;

  const int arow0 = ((h << 4) + lq) * RS + (g << 3);
  const int vcol  = (h << 4) + (g << 2);
  const float* r2p = r2 + (b << 12) + (h << 4) + (g << 2);
  const ush* kth_b = kt_hi + (((size_t)(b << 12)) << 8);
  const ush* ktl_b = kt_lo + (((size_t)(b << 12)) << 8);
  const ush* vt_b  = vt + (((size_t)(b << 7)) << 13);

  for (int t = 0; t < 128; ++t) {
    const int j0 = t << 5;
    __syncthreads();
    // stage K (8 b128) + V (4 b128), all coalesced copies
    const ush* gkh = kth_b + ((size_t)j0 << 8);
    const ush* gkl = ktl_b + ((size_t)j0 << 8);
    const ush* gv  = vt_b + ((size_t)t << 13);
#pragma unroll
    for (int m = 0; m < 4; ++m) {
      int id = tid + (m << 8);
      int row = id >> 5, cch = id & 31;
      u32x4 vh = *(const u32x4*)(gkh + (row << 8) + (cch << 3));
      u32x4 vl = *(const u32x4*)(gkl + (row << 8) + (cch << 3));
      *(u32x4*)(Khi + row * RS + (cch << 3)) = vh;
      *(u32x4*)(Klo + row * RS + (cch << 3)) = vl;
    }
#pragma unroll
    for (int m = 0; m < 4; ++m) {
      int id = tid + (m << 8);
      int c = id >> 2, q = id & 3;
      u32x4 vv = *(const u32x4*)(gv + (id << 3));
      *(u32x4*)(V + c * RSV + (q << 3)) = vv;
    }
    __syncthreads();

    // S^T = K·Q (3-pass)
    f32x4 aS = {0.f, 0.f, 0.f, 0.f};
#pragma unroll
    for (int cs = 0; cs < 8; ++cs) {
      Frag8 Ah, Al;
      Ah.u4 = *(const u32x4*)(Khi + arow0 + (cs << 5));
      Al.u4 = *(const u32x4*)(Klo + arow0 + (cs << 5));
      aS = MFMA32(Ah.f, QBh[cs].f, aS);
      aS = MFMA32(Ah.f, QBl[cs].f, aS);
      aS = MFMA32(Al.f, QBh[cs].f, aS);
    }

    // online softmax over this wave's 16 j
    float4 r2v = *(const float4*)(r2p + j0);
    float s0 = aS[0] + r2v.x, s1 = aS[1] + r2v.y;
    float s2 = aS[2] + r2v.z, s3 = aS[3] + r2v.w;
    float mx = fmaxf(fmaxf(s0, s1), fmaxf(s2, s3));
    mx = fmaxf(mx, __shfl_xor(mx, 16));
    mx = fmaxf(mx, __shfl_xor(mx, 32));
    float mn  = fmaxf(m_run, mx);
    float scl = __expf(m_run - mn);
    float p0 = __expf(s0 - mn), p1 = __expf(s1 - mn);
    float p2 = __expf(s2 - mn), p3 = __expf(s3 - mn);
    float rs = p0 + p1 + p2 + p3;
    rs += __shfl_xor(rs, 16);
    rs += __shfl_xor(rs, 32);
    l_run = l_run * scl + rs;
    m_run = mn;

    Frag4 Pf;
    Pf.u2.x = pkrtz(p0, p1);
    Pf.u2.y = pkrtz(p2, p3);

#pragma unroll
    for (int ct = 0; ct < 16; ++ct) {
      vacc[ct][0] *= scl; vacc[ct][1] *= scl;
      vacc[ct][2] *= scl; vacc[ct][3] *= scl;
    }
#pragma unroll
    for (int ct = 0; ct < 16; ++ct) {
      Frag4 Vf;
      Vf.u2 = *(const u32x2*)(V + (lq + (ct << 4)) * RSV + vcol);
      vacc[ct] = MFMA16(Vf.f, Pf.f, vacc[ct]);
    }
  }

  // ---- merge j-halves, normalize, store ----
  __syncthreads();
  float* Cmb = (float*)lds;                          // [2][256][17] f32 (34816B)
  float* Msm = (float*)((char*)lds + 34816);
  float* Lsm = Msm + 64;
  if (g == 0) {
    Msm[p * 32 + h * 16 + lq] = m_run;
    Lsm[p * 32 + h * 16 + lq] = l_run;
  }
  __syncthreads();
  float mo  = Msm[p * 32 + (1 - h) * 16 + lq];
  float lo2 = Lsm[p * 32 + (1 - h) * 16 + lq];
  float mt    = fmaxf(m_run, mo);
  float aSelf = __expf(m_run - mt);
  float l_tot = l_run * aSelf + lo2 * __expf(mo - mt);

  if (h == 0) {
    float* cb_ = Cmb + p * (CC * RSC);
#pragma unroll
    for (int ct = 0; ct < 16; ++ct)
#pragma unroll
      for (int r = 0; r < 4; ++r)
        cb_[((ct << 4) + (g << 2) + r) * RSC + lq] = vacc[ct][r] * aSelf;
  }
  __syncthreads();
  if (h == 1) {
    const float* cb_ = Cmb + p * (CC * RSC);
    float inv = 1.f / l_tot;
    float* ob = out + ((size_t)b << 20) + i0 + (p << 4) + lq;
#pragma unroll
    for (int ct = 0; ct < 16; ++ct)
#pragma unroll
      for (int r = 0; r < 4; ++r) {
        int c = (ct << 4) + (g << 2) + r;
        ob[(size_t)c << 12] = (vacc[ct][r] * aSelf + cb_[c * RSC + lq]) * inv;
      }
  }
}

// ---------------- fallback (round-4 kernel, used if ws too small) ----------------
__launch_bounds__(256, 2)
__global__ void k_attn_fb(const float* __restrict__ x1, const float* __restrict__ x2,
                          const float* __restrict__ M, const float* __restrict__ r2,
                          float* __restrict__ out) {
  extern __shared__ ush lds[];
  ush*   A_h   = lds;
  float* A_f   = (float*)lds;
  ush*   B_h   = lds + 20480;
  float* B_f   = (float*)(lds + 20480);

  const int tid  = threadIdx.x;
  const int lane = tid & 63;
  const int w    = tid >> 6;
  const int p    = w >> 1;
  const int h    = w & 1;
  const int g    = lane >> 4;
  const int lq   = lane & 15;

  int bid = (int)blockIdx.x;
  bid = (bid & 7) * 64 + (bid >> 3);
  const int b  = bid >> 7;
  const int i0 = (bid & 127) << 5;

  const float* x1b = x1 + ((size_t)b << 20);
  const float* x2b = x2 + ((size_t)b << 20);

  {
    const int jf = tid & 7;
    const int c0 = tid >> 3;
#pragma unroll
    for (int m = 0; m < 8; ++m) {
      int c = c0 + (m << 5);
      float4 v = *(const float4*)(x1b + ((size_t)c << 12) + i0 + (jf << 2));
      *(float4*)(A_f + c * RSV + (jf << 2)) = v;
    }
  }
  __syncthreads();
  {
    const int tc = tid & 63;
    const int tq = tid >> 6;
    float acc[4][8];
#pragma unroll
    for (int q = 0; q < 4; ++q)
#pragma unroll
      for (int e = 0; e < 8; ++e) acc[q][e] = 0.f;
#pragma unroll 4
    for (int c = 0; c < CC; ++c) {
      float4 mv = *(const float4*)(M + c * CC + (tc << 2));
      float4 xa = *(const float4*)(A_f + c * RSV + (tq << 3));
      float4 xb = *(const float4*)(A_f + c * RSV + (tq << 3) + 4);
      float xs[8] = {xa.x, xa.y, xa.z, xa.w, xb.x, xb.y, xb.z, xb.w};
#pragma unroll
      for (int e = 0; e < 8; ++e) {
        acc[0][e] += mv.x * xs[e];
        acc[1][e] += mv.y * xs[e];
        acc[2][e] += mv.z * xs[e];
        acc[3][e] += mv.w * xs[e];
      }
    }
#pragma unroll
    for (int e = 0; e < 8; ++e) {
      float4 v = make_float4(acc[0][e], acc[1][e], acc[2][e], acc[3][e]);
      *(float4*)(B_f + ((tq << 3) + e) * RS + (tc << 2)) = v;
    }
  }
  __syncthreads();
  {
    ush* Qhi = A_h;
    ush* Qlo = A_h + 32 * RS;
    const int i  = tid >> 3;
    const int ch = tid & 7;
    const float* src = B_f + i * RS + (ch << 5);
    u32 hi[16], lo[16];
#pragma unroll
    for (int k = 0; k < 8; ++k) {
      float4 a = *(const float4*)(src + (k << 2));
      u32 h0 = pkrtz(a.x, a.y), h1 = pkrtz(a.z, a.w);
      hi[2 * k]     = h0;
      hi[2 * k + 1] = h1;
      float l0 = a.x - h2fu(h0), l1 = a.y - h2fu(h0 >> 16);
      float l2 = a.z - h2fu(h1), l3 = a.w - h2fu(h1 >> 16);
      lo[2 * k]     = pkrtz(l0, l1);
      lo[2 * k + 1] = pkrtz(l2, l3);
    }
#pragma unroll
    for (int m = 0; m < 4; ++m) {
      u32x4 vh; vh.x = hi[4*m]; vh.y = hi[4*m+1]; vh.z = hi[4*m+2]; vh.w = hi[4*m+3];
      u32x4 vl; vl.x = lo[4*m]; vl.y = lo[4*m+1]; vl.z = lo[4*m+2]; vl.w = lo[4*m+3];
      *(u32x4*)(Qhi + i * RS + (ch << 5) + (m << 3)) = vh;
      *(u32x4*)(Qlo + i * RS + (ch << 5) + (m << 3)) = vl;
    }
  }
  __syncthreads();

  Frag8 QBh[8], QBl[8];
  {
    const ush* Qhi = A_h;
    const ush* Qlo = A_h + 32 * RS;
    const int qrow = ((p << 4) + lq) * RS;
#pragma unroll
    for (int cs = 0; cs < 8; ++cs) {
      QBh[cs].u4 = *(const u32x4*)(Qhi + qrow + (cs << 5) + (g << 3));
      QBl[cs].u4 = *(const u32x4*)(Qlo + qrow + (cs << 5) + (g << 3));
    }
  }

  ush* Khi = A_h;
  ush* Klo = A_h + 32 * RS;
  ush* V   = B_h;

  f32x4 vacc[16];
#pragma unroll
  for (int ct = 0; ct < 16; ++ct) vacc[ct] = (f32x4){0.f, 0.f, 0.f, 0.f};
  float m_run = -3.0e38f, l_run = 0.f;

  const int jj  = tid & 31;
  const int cq4 = (tid >> 5) << 2;
  const int jf  = tid & 7;
  const int cV  = tid >> 3;
  const int arow0 = ((h << 4) + lq) * RS + (g << 3);
  const int vcol  = (h << 4) + (g << 2);
  const float* r2p = r2 + (b << 12) + (h << 4) + (g << 2);

  for (int t = 0; t < 128; ++t) {
    const int j0 = t << 5;
    __syncthreads();
#pragma unroll
    for (int m = 0; m < 8; ++m) {
      int c = cq4 + (m << 5);
      const float* xp = x2b + ((size_t)c << 12) + j0 + jj;
      float v0 = xp[0];
      float v1 = xp[4096];
      float v2 = xp[8192];
      float v3 = xp[12288];
      u32 h0 = pkrtz(v0, v1), h1 = pkrtz(v2, v3);
      float l0 = v0 - h2fu(h0), l1 = v1 - h2fu(h0 >> 16);
      float l2 = v2 - h2fu(h1), l3 = v3 - h2fu(h1 >> 16);
      u32x2 hw; hw.x = h0; hw.y = h1;
      u32x2 lw; lw.x = pkrtz(l0, l1); lw.y = pkrtz(l2, l3);
      *(u32x2*)(Khi + jj * RS + c) = hw;
      *(u32x2*)(Klo + jj * RS + c) = lw;
    }
#pragma unroll
    for (int m = 0; m < 8; ++m) {
      int c = cV + (m << 5);
      float4 v = *(const float4*)(x2b + ((size_t)c << 12) + j0 + (jf << 2));
      u32x2 hw; hw.x = pkrtz(v.x, v.y); hw.y = pkrtz(v.z, v.w);
      *(u32x2*)(V + c * RSV + (jf << 2)) = hw;
    }
    __syncthreads();

    f32x4 aS = {0.f, 0.f, 0.f, 0.f};
#pragma unroll
    for (int cs = 0; cs < 8; ++cs) {
      Frag8 Ah, Al;
      Ah.u4 = *(const u32x4*)(Khi + arow0 + (cs << 5));
      Al.u4 = *(const u32x4*)(Klo + arow0 + (cs << 5));
      aS = MFMA32(Ah.f, QBh[cs].f, aS);
      aS = MFMA32(Ah.f, QBl[cs].f, aS);
      aS = MFMA32(Al.f, QBh[cs].f, aS);
    }

    float4 r2v = *(const float4*)(r2p + j0);
    float s0 = aS[0] + r2v.x, s1 = aS[1] + r2v.y;
    float s2 = aS[2] + r2v.z, s3 = aS[3] + r2v.w;
    float mx = fmaxf(fmaxf(s0, s1), fmaxf(s2, s3));
    mx = fmaxf(mx, __shfl_xor(mx, 16));
    mx = fmaxf(mx, __shfl_xor(mx, 32));
    float mn  = fmaxf(m_run, mx);
    float scl = __expf(m_run - mn);
    float p0 = __expf(s0 - mn), p1 = __expf(s1 - mn);
    float p2 = __expf(s2 - mn), p3 = __expf(s3 - mn);
    float rs = p0 + p1 + p2 + p3;
    rs += __shfl_xor(rs, 16);
    rs += __shfl_xor(rs, 32);
    l_run = l_run * scl + rs;
    m_run = mn;

    Frag4 Pf;
    Pf.u2.x = pkrtz(p0, p1);
    Pf.u2.y = pkrtz(p2, p3);

#pragma unroll
    for (int ct = 0; ct < 16; ++ct) {
      vacc[ct][0] *= scl; vacc[ct][1] *= scl;
      vacc[ct][2] *= scl; vacc[ct][3] *= scl;
    }
#pragma unroll
    for (int ct = 0; ct < 16; ++ct) {
      Frag4 Vf;
      Vf.u2 = *(const u32x2*)(V + (lq + (ct << 4)) * RSV + vcol);
      vacc[ct] = MFMA16(Vf.f, Pf.f, vacc[ct]);
    }
  }

  __syncthreads();
  float* Msm = B_f;
  float* Lsm = B_f + 64;
  if (g == 0) {
    Msm[p * 32 + h * 16 + lq] = m_run;
    Lsm[p * 32 + h * 16 + lq] = l_run;
  }
  __syncthreads();
  float mo  = Msm[p * 32 + (1 - h) * 16 + lq];
  float lo2 = Lsm[p * 32 + (1 - h) * 16 + lq];
  float mt    = fmaxf(m_run, mo);
  float aSelf = __expf(m_run - mt);
  float l_tot = l_run * aSelf + lo2 * __expf(mo - mt);

  float* Cmb = A_f;
  if (h == 0) {
    float* cb_ = Cmb + p * (CC * RSC);
#pragma unroll
    for (int ct = 0; ct < 16; ++ct)
#pragma unroll
      for (int r = 0; r < 4; ++r)
        cb_[((ct << 4) + (g << 2) + r) * RSC + lq] = vacc[ct][r] * aSelf;
  }
  __syncthreads();
  if (h == 1) {
    const float* cb_ = Cmb + p * (CC * RSC);
    float inv = 1.f / l_tot;
    float* ob = out + ((size_t)b << 20) + i0 + (p << 4) + lq;
#pragma unroll
    for (int ct = 0; ct < 16; ++ct)
#pragma unroll
      for (int r = 0; r < 4; ++r) {
        int c = (ct << 4) + (g << 2) + r;
        ob[(size_t)c << 12] = (vacc[ct][r] * aSelf + cb_[c * RSC + lq]) * inv;
      }
  }
}

extern "C" void kernel_launch(void* const* d_in, const int* in_sizes, int n_in,
                              void* d_out, int out_size, void* d_ws, size_t ws_size,
                              hipStream_t stream) {
  const float* x1 = (const float*)d_in[0];
  const float* x2 = (const float*)d_in[1];
  const float* w1 = (const float*)d_in[2];
  const float* b1 = (const float*)d_in[3];
  const float* w2 = (const float*)d_in[4];
  // b2 (d_in[5]) contributes only row-constant energy terms -> cancels in softmax.

  float* M  = (float*)d_ws;            // 256KB
  float* g  = M + 65536;               // 1KB
  float* r2 = g + 256;                 // 64KB
  float* outp = (float*)d_out;

  const size_t base_f = 65536 + 256 + 16384;             // floats used so far
  const size_t need = base_f * 4 + 3ull * 8388608;       // + KT_hi/KT_lo/V (8MB each)

  k_prep<<<CC, 256, 0, stream>>>(w1, w2, b1, M, g);
  k_r2<<<BB * NN / 256, 256, 0, stream>>>(x2, g, r2);

  if (ws_size >= need) {
    ush* kt_hi = (ush*)(r2 + 16384);
    ush* kt_lo = kt_hi + 4194304;
    ush* vt    = kt_lo + 4194304;
    const int LDS_BYTES = 54272;
    (void)hipFuncSetAttribute((const void*)k_attn,
                              hipFuncAttributeMaxDynamicSharedMemorySize, LDS_BYTES);
    k_cvt<<<BB * (NN / 32), 256, 0, stream>>>(x2, kt_hi, kt_lo, vt);
    k_attn<<<BB * (NN / 32), 256, LDS_BYTES, stream>>>(x1, kt_hi, kt_lo, vt, M, r2, outp);
  } else {
    const int LDS_BYTES = 74752;
    (void)hipFuncSetAttribute((const void*)k_attn_fb,
                              hipFuncAttributeMaxDynamicSharedMemorySize, LDS_BYTES);
    k_attn_fb<<<BB * (NN / 32), 256, LDS_BYTES, stream>>>(x1, x2, M, r2, outp);
  }
  (void)in_sizes; (void)n_in; (void)out_size; (void)ws_size;
}

// Round 6
// 276.460 us; speedup vs baseline: 2.5434x; 2.5434x over previous
//
#include <hip/hip_runtime.h>

typedef _Float16 f16;
typedef _Float16 f16x8 __attribute__((ext_vector_type(8)));
typedef _Float16 f16x4 __attribute__((ext_vector_type(4)));
typedef float    f32x4 __attribute__((ext_vector_type(4)));
typedef unsigned int u32;
typedef u32 u32x2 __attribute__((ext_vector_type(2)));
typedef u32 u32x4 __attribute__((ext_vector_type(4)));
typedef unsigned short ush;

#define CC 256
#define NN 4096
#define BB 4
#define RS 264          // fallback kernel row stride
#define RSV 40          // fallback V stride
#define RSC 17          // combine buffer stride (f32)

union Frag8 { u32x4 u4; f16x8 f; };
union Frag4 { u32x2 u2; f16x4 f; };

static __device__ __forceinline__ u32 pkrtz(float a, float b) {
  auto t = __builtin_amdgcn_cvt_pkrtz(a, b);
  return __builtin_bit_cast(u32, t);
}
static __device__ __forceinline__ float h2fu(u32 u) {
  f16 h = __builtin_bit_cast(f16, (ush)(u & 0xffffu));
  return (float)h;
}

static __device__ __forceinline__ void gload16(const ush* g, ush* l) {
  __builtin_amdgcn_global_load_lds(
      (const __attribute__((address_space(1))) u32*)g,
      (__attribute__((address_space(3))) u32*)l, 16, 0, 0);
}

#define MFMA32(A, B, C) __builtin_amdgcn_mfma_f32_16x16x32_f16((A), (B), (C), 0, 0, 0)
#define MFMA16(A, B, C) __builtin_amdgcn_mfma_f32_16x16x16f16((A), (B), (C), 0, 0, 0)

// K1: M[c][cp] = sum_o w1[o,c]*w2[o,cp] ; g[cp] = sum_o b1[o]*w2[o,cp]
__global__ void k_prep(const float* __restrict__ w1, const float* __restrict__ w2,
                       const float* __restrict__ b1, float* __restrict__ M,
                       float* __restrict__ g) {
  const int c  = blockIdx.x;
  const int cp = threadIdx.x;
  float acc = 0.f;
#pragma unroll 8
  for (int o = 0; o < CC; ++o)
    acc += w1[o * CC + c] * w2[o * CC + cp];
  M[c * CC + cp] = acc;
  if (c == 0) {
    float ga = 0.f;
    for (int o = 0; o < CC; ++o)
      ga += b1[o] * w2[o * CC + cp];
    g[cp] = ga;
  }
}

// K2: r2[b*N+j] = sum_c g[c] * x2[b,c,j]
__global__ void k_r2(const float* __restrict__ x2, const float* __restrict__ g,
                     float* __restrict__ r2) {
  const int jg = blockIdx.x * 256 + threadIdx.x;
  const int b  = jg >> 12;
  const int j  = jg & (NN - 1);
  const float* xp = x2 + (((size_t)(b * CC)) << 12) + j;
  float acc = 0.f;
#pragma unroll 8
  for (int c = 0; c < CC; ++c)
    acc += g[c] * xp[(size_t)c << 12];
  r2[jg] = acc;
}

// K-cvt: build per-tile LDS byte-images (pre-swizzled) for K^T (fp16 hi) and V.
// K image (16KB/tile): row j (32 rows, 512B): target slot st (16B) holds data
//   slot s = st ^ (j&7)  = halves c = 8s..8s+7 of K^T row j.
// V image (16KB/tile): row c (256 rows, 64B): target 8B slot st holds data slot
//   s = st ^ (c&7) = j-halves 4s..4s+3.
__global__ void k_cvt(const float* __restrict__ x2, ush* __restrict__ kimg,
                      ush* __restrict__ vimg) {
  __shared__ float Xs[256 * 37];
  const int tid = threadIdx.x;
  const int b   = blockIdx.x >> 7;
  const int jt  = blockIdx.x & 127;
  const int j0  = jt << 5;
  const float* x2b = x2 + ((size_t)b << 20);
  {
    const int jf = tid & 7, c0 = tid >> 3;
#pragma unroll
    for (int m = 0; m < 8; ++m) {
      int c = c0 + (m << 5);
      float4 v = *(const float4*)(x2b + ((size_t)c << 12) + j0 + (jf << 2));
      *(float4*)(Xs + c * 37 + (jf << 2)) = v;
    }
  }
  __syncthreads();
  const size_t tile = ((size_t)blockIdx.x) << 13;   // halves
  {
    ush* kp = kimg + tile;
#pragma unroll
    for (int m = 0; m < 4; ++m) {
      int idx = tid + (m << 8);
      int j = idx >> 5, st = idx & 31;
      int s = st ^ (j & 7);
      u32 hw[4];
#pragma unroll
      for (int k = 0; k < 4; ++k) {
        float a  = Xs[(8 * s + 2 * k) * 37 + j];
        float c2 = Xs[(8 * s + 2 * k + 1) * 37 + j];
        hw[k] = pkrtz(a, c2);
      }
      u32x4 v; v.x = hw[0]; v.y = hw[1]; v.z = hw[2]; v.w = hw[3];
      *(u32x4*)(kp + (idx << 3)) = v;
    }
  }
  {
    ush* vp = vimg + tile;
#pragma unroll
    for (int m = 0; m < 4; ++m) {
      int idx = tid + (m << 8);
      int c = idx >> 2, a2 = idx & 3;
      int s0 = (2 * a2) ^ (c & 7);
      int s1 = (2 * a2 + 1) ^ (c & 7);
      u32x4 v;
      v.x = pkrtz(Xs[c * 37 + 4 * s0],     Xs[c * 37 + 4 * s0 + 1]);
      v.y = pkrtz(Xs[c * 37 + 4 * s0 + 2], Xs[c * 37 + 4 * s0 + 3]);
      v.z = pkrtz(Xs[c * 37 + 4 * s1],     Xs[c * 37 + 4 * s1 + 1]);
      v.w = pkrtz(Xs[c * 37 + 4 * s1 + 2], Xs[c * 37 + 4 * s1 + 3]);
      *(u32x4*)(vp + (idx << 3)) = v;
    }
  }
}

// K3: Q-prep + flash attention; DMA double-buffered staging, 2-pass S.
__launch_bounds__(256, 2)
__global__ void k_attn(const float* __restrict__ x1, const ush* __restrict__ kimg,
                       const ush* __restrict__ vimg, const float* __restrict__ M,
                       const float* __restrict__ r2, float* __restrict__ out) {
  extern __shared__ ush lds[];
  // buf0 @0 halves (K 0..8191, V 8192..16383), buf1 @16384; Msm/Lsm @32768 halves.
  const int tid  = threadIdx.x;
  const int lane = tid & 63;
  const int w    = tid >> 6;
  const int p    = w >> 1;
  const int h    = w & 1;
  const int g    = lane >> 4;
  const int lq   = lane & 15;

  int bid = (int)blockIdx.x;
  bid = (bid & 7) * 64 + (bid >> 3);        // bijective XCD swizzle (512 = 8*64)
  const int b  = bid >> 7;
  const int i0 = (bid & 127) << 5;

  const float* x1b = x1 + ((size_t)b << 20);

  // ---- Q-prep (VALU f32, two 16-i passes); x1f in buf0, Qhi/Qlo in buf1 ----
  float* x1f = (float*)lds;                 // [256][20] f32
  ush* Qhi = lds + 16384;                   // [32][256] halves
  ush* Qlo = lds + 16384 + 8192;
  for (int ih = 0; ih < 2; ++ih) {
    {
      const int jf = tid & 3, c0 = tid >> 2;
#pragma unroll
      for (int m = 0; m < 4; ++m) {
        int c = c0 + (m << 6);
        float4 v = *(const float4*)(x1b + ((size_t)c << 12) + i0 + (ih << 4) + (jf << 2));
        *(float4*)(x1f + c * 20 + (jf << 2)) = v;
      }
    }
    __syncthreads();
    {
      const int tc = tid & 63, tq = tid >> 6;
      float acc[4][4];
#pragma unroll
      for (int q = 0; q < 4; ++q)
#pragma unroll
        for (int e = 0; e < 4; ++e) acc[q][e] = 0.f;
#pragma unroll 4
      for (int c = 0; c < CC; ++c) {
        float4 mv = *(const float4*)(M + c * CC + (tc << 2));
        float4 xs = *(const float4*)(x1f + c * 20 + (tq << 2));
        float xv[4] = {xs.x, xs.y, xs.z, xs.w};
#pragma unroll
        for (int e = 0; e < 4; ++e) {
          acc[0][e] += mv.x * xv[e];
          acc[1][e] += mv.y * xv[e];
          acc[2][e] += mv.z * xv[e];
          acc[3][e] += mv.w * xv[e];
        }
      }
#pragma unroll
      for (int e = 0; e < 4; ++e) {
        int i = (ih << 4) + (tq << 2) + e;
        u32 h0 = pkrtz(acc[0][e], acc[1][e]);
        u32 h1 = pkrtz(acc[2][e], acc[3][e]);
        float l0 = acc[0][e] - h2fu(h0), l1 = acc[1][e] - h2fu(h0 >> 16);
        float l2 = acc[2][e] - h2fu(h1), l3 = acc[3][e] - h2fu(h1 >> 16);
        u32x2 hw; hw.x = h0; hw.y = h1;
        u32x2 lw; lw.x = pkrtz(l0, l1); lw.y = pkrtz(l2, l3);
        *(u32x2*)(Qhi + (i << 8) + (tc << 2)) = hw;
        *(u32x2*)(Qlo + (i << 8) + (tc << 2)) = lw;
      }
    }
    __syncthreads();
  }

  // ---- preload Q fragments (one-time) ----
  Frag8 QBh[8], QBl[8];
  {
    const int qoff = ((p << 4) + lq) << 8;
#pragma unroll
    for (int cs = 0; cs < 8; ++cs) {
      QBh[cs].u4 = *(const u32x4*)(Qhi + qoff + (cs << 5) + (g << 3));
      QBl[cs].u4 = *(const u32x4*)(Qlo + qoff + (cs << 5) + (g << 3));
    }
  }
  __syncthreads();

  // ---- main flash loop (DMA double-buffer) ----
  f32x4 vacc[16];
#pragma unroll
  for (int ct = 0; ct < 16; ++ct) vacc[ct] = (f32x4){0.f, 0.f, 0.f, 0.f};
  float m_run = -3.0e38f, l_run = 0.f;

  const int jrow = (h << 4) + lq;
  const int sx   = jrow & 7;
  const int koff = jrow << 8;                       // halves
  const int vq   = ((h << 2) + g) ^ (lq & 7);
  const float* r2p = r2 + (b << 12) + (h << 4) + (g << 2);
  const size_t bt = (size_t)(b << 7);

  // prologue: stage tile 0 into buf0
  {
    const ush* gk = kimg + (bt << 13);
    const ush* gv = vimg + (bt << 13);
#pragma unroll
    for (int m = 0; m < 4; ++m) {
      int idx = tid + (m << 8);
      gload16(gk + (idx << 3), lds + (idx << 3));
      gload16(gv + (idx << 3), lds + 8192 + (idx << 3));
    }
  }
  __syncthreads();

  for (int t = 0; t < 128; ++t) {
    const int cur = (t & 1) << 14;
    if (t + 1 < 128) {
      const int nxt = ((t + 1) & 1) << 14;
      const ush* gk = kimg + ((bt + t + 1) << 13);
      const ush* gv = vimg + ((bt + t + 1) << 13);
#pragma unroll
      for (int m = 0; m < 4; ++m) {
        int idx = tid + (m << 8);
        gload16(gk + (idx << 3), lds + nxt + (idx << 3));
        gload16(gv + (idx << 3), lds + nxt + 8192 + (idx << 3));
      }
    }
    const ush* kb = lds + cur;
    const ush* vb = lds + cur + 8192;

    // S = Khi·Qhi + Khi·Qlo  (two independent chains)
    f32x4 a1 = {0.f, 0.f, 0.f, 0.f}, a2 = {0.f, 0.f, 0.f, 0.f};
#pragma unroll
    for (int cs = 0; cs < 8; ++cs) {
      int st = ((cs << 2) + g) ^ sx;
      Frag8 Ah; Ah.u4 = *(const u32x4*)(kb + koff + (st << 3));
      a1 = MFMA32(Ah.f, QBh[cs].f, a1);
      a2 = MFMA32(Ah.f, QBl[cs].f, a2);
    }

    // online softmax (rows i = 16p+lq; js = j0 + 16h + 4g + r)
    float4 r2v = *(const float4*)(r2p + (t << 5));
    float s0 = a1[0] + a2[0] + r2v.x, s1 = a1[1] + a2[1] + r2v.y;
    float s2 = a1[2] + a2[2] + r2v.z, s3 = a1[3] + a2[3] + r2v.w;
    float mx = fmaxf(fmaxf(s0, s1), fmaxf(s2, s3));
    mx = fmaxf(mx, __shfl_xor(mx, 16));
    mx = fmaxf(mx, __shfl_xor(mx, 32));
    float mn = fmaxf(m_run, mx);
    int stb = (mn == m_run) ? 1 : 0;
    float scl = __expf(m_run - mn);
    float p0 = __expf(s0 - mn), p1 = __expf(s1 - mn);
    float p2 = __expf(s2 - mn), p3 = __expf(s3 - mn);
    float rs = p0 + p1 + p2 + p3;
    rs += __shfl_xor(rs, 16);
    rs += __shfl_xor(rs, 32);
    l_run = l_run * scl + rs;
    m_run = mn;

    Frag4 Pf;
    Pf.u2.x = pkrtz(p0, p1);
    Pf.u2.y = pkrtz(p2, p3);

    if (!__all(stb)) {
#pragma unroll
      for (int ct = 0; ct < 16; ++ct) {
        vacc[ct][0] *= scl; vacc[ct][1] *= scl;
        vacc[ct][2] *= scl; vacc[ct][3] *= scl;
      }
    }
#pragma unroll
    for (int ct = 0; ct < 16; ++ct) {
      Frag4 Vf;
      Vf.u2 = *(const u32x2*)(vb + ((lq + (ct << 4)) << 5) + (vq << 2));
      vacc[ct] = MFMA16(Vf.f, Pf.f, vacc[ct]);
    }
    __syncthreads();
  }

  // ---- merge j-halves, normalize, store ----
  float* Cmb = (float*)lds;                          // [2][256][17] f32
  float* Msm = (float*)(lds + 32768);
  float* Lsm = Msm + 64;
  if (g == 0) {
    Msm[p * 32 + h * 16 + lq] = m_run;
    Lsm[p * 32 + h * 16 + lq] = l_run;
  }
  __syncthreads();
  float mo  = Msm[p * 32 + (1 - h) * 16 + lq];
  float lo2 = Lsm[p * 32 + (1 - h) * 16 + lq];
  float mt    = fmaxf(m_run, mo);
  float aSelf = __expf(m_run - mt);
  float l_tot = l_run * aSelf + lo2 * __expf(mo - mt);

  if (h == 0) {
    float* cb_ = Cmb + p * (CC * RSC);
#pragma unroll
    for (int ct = 0; ct < 16; ++ct)
#pragma unroll
      for (int r = 0; r < 4; ++r)
        cb_[((ct << 4) + (g << 2) + r) * RSC + lq] = vacc[ct][r] * aSelf;
  }
  __syncthreads();
  if (h == 1) {
    const float* cb_ = Cmb + p * (CC * RSC);
    float inv = 1.f / l_tot;
    float* ob = out + ((size_t)b << 20) + i0 + (p << 4) + lq;
#pragma unroll
    for (int ct = 0; ct < 16; ++ct)
#pragma unroll
      for (int r = 0; r < 4; ++r) {
        int c = (ct << 4) + (g << 2) + r;
        ob[(size_t)c << 12] = (vacc[ct][r] * aSelf + cb_[c * RSC + lq]) * inv;
      }
  }
}

// ---------------- fallback (round-4 kernel, used if ws too small) ----------------
__launch_bounds__(256, 2)
__global__ void k_attn_fb(const float* __restrict__ x1, const float* __restrict__ x2,
                          const float* __restrict__ M, const float* __restrict__ r2,
                          float* __restrict__ out) {
  extern __shared__ ush lds[];
  ush*   A_h   = lds;
  float* A_f   = (float*)lds;
  ush*   B_h   = lds + 20480;
  float* B_f   = (float*)(lds + 20480);

  const int tid  = threadIdx.x;
  const int lane = tid & 63;
  const int w    = tid >> 6;
  const int p    = w >> 1;
  const int h    = w & 1;
  const int g    = lane >> 4;
  const int lq   = lane & 15;

  int bid = (int)blockIdx.x;
  bid = (bid & 7) * 64 + (bid >> 3);
  const int b  = bid >> 7;
  const int i0 = (bid & 127) << 5;

  const float* x1b = x1 + ((size_t)b << 20);
  const float* x2b = x2 + ((size_t)b << 20);

  {
    const int jf = tid & 7;
    const int c0 = tid >> 3;
#pragma unroll
    for (int m = 0; m < 8; ++m) {
      int c = c0 + (m << 5);
      float4 v = *(const float4*)(x1b + ((size_t)c << 12) + i0 + (jf << 2));
      *(float4*)(A_f + c * RSV + (jf << 2)) = v;
    }
  }
  __syncthreads();
  {
    const int tc = tid & 63;
    const int tq = tid >> 6;
    float acc[4][8];
#pragma unroll
    for (int q = 0; q < 4; ++q)
#pragma unroll
      for (int e = 0; e < 8; ++e) acc[q][e] = 0.f;
#pragma unroll 4
    for (int c = 0; c < CC; ++c) {
      float4 mv = *(const float4*)(M + c * CC + (tc << 2));
      float4 xa = *(const float4*)(A_f + c * RSV + (tq << 3));
      float4 xb = *(const float4*)(A_f + c * RSV + (tq << 3) + 4);
      float xs[8] = {xa.x, xa.y, xa.z, xa.w, xb.x, xb.y, xb.z, xb.w};
#pragma unroll
      for (int e = 0; e < 8; ++e) {
        acc[0][e] += mv.x * xs[e];
        acc[1][e] += mv.y * xs[e];
        acc[2][e] += mv.z * xs[e];
        acc[3][e] += mv.w * xs[e];
      }
    }
#pragma unroll
    for (int e = 0; e < 8; ++e) {
      float4 v = make_float4(acc[0][e], acc[1][e], acc[2][e], acc[3][e]);
      *(float4*)(B_f + ((tq << 3) + e) * RS + (tc << 2)) = v;
    }
  }
  __syncthreads();
  {
    ush* Qhi = A_h;
    ush* Qlo = A_h + 32 * RS;
    const int i  = tid >> 3;
    const int ch = tid & 7;
    const float* src = B_f + i * RS + (ch << 5);
    u32 hi[16], lo[16];
#pragma unroll
    for (int k = 0; k < 8; ++k) {
      float4 a = *(const float4*)(src + (k << 2));
      u32 h0 = pkrtz(a.x, a.y), h1 = pkrtz(a.z, a.w);
      hi[2 * k]     = h0;
      hi[2 * k + 1] = h1;
      float l0 = a.x - h2fu(h0), l1 = a.y - h2fu(h0 >> 16);
      float l2 = a.z - h2fu(h1), l3 = a.w - h2fu(h1 >> 16);
      lo[2 * k]     = pkrtz(l0, l1);
      lo[2 * k + 1] = pkrtz(l2, l3);
    }
#pragma unroll
    for (int m = 0; m < 4; ++m) {
      u32x4 vh; vh.x = hi[4*m]; vh.y = hi[4*m+1]; vh.z = hi[4*m+2]; vh.w = hi[4*m+3];
      u32x4 vl; vl.x = lo[4*m]; vl.y = lo[4*m+1]; vl.z = lo[4*m+2]; vl.w = lo[4*m+3];
      *(u32x4*)(Qhi + i * RS + (ch << 5) + (m << 3)) = vh;
      *(u32x4*)(Qlo + i * RS + (ch << 5) + (m << 3)) = vl;
    }
  }
  __syncthreads();

  Frag8 QBh[8], QBl[8];
  {
    const ush* Qhi = A_h;
    const ush* Qlo = A_h + 32 * RS;
    const int qrow = ((p << 4) + lq) * RS;
#pragma unroll
    for (int cs = 0; cs < 8; ++cs) {
      QBh[cs].u4 = *(const u32x4*)(Qhi + qrow + (cs << 5) + (g << 3));
      QBl[cs].u4 = *(const u32x4*)(Qlo + qrow + (cs << 5) + (g << 3));
    }
  }

  ush* Khi = A_h;
  ush* Klo = A_h + 32 * RS;
  ush* V   = B_h;

  f32x4 vacc[16];
#pragma unroll
  for (int ct = 0; ct < 16; ++ct) vacc[ct] = (f32x4){0.f, 0.f, 0.f, 0.f};
  float m_run = -3.0e38f, l_run = 0.f;

  const int jj  = tid & 31;
  const int cq4 = (tid >> 5) << 2;
  const int jf  = tid & 7;
  const int cV  = tid >> 3;
  const int arow0 = ((h << 4) + lq) * RS + (g << 3);
  const int vcol  = (h << 4) + (g << 2);
  const float* r2p = r2 + (b << 12) + (h << 4) + (g << 2);

  for (int t = 0; t < 128; ++t) {
    const int j0 = t << 5;
    __syncthreads();
#pragma unroll
    for (int m = 0; m < 8; ++m) {
      int c = cq4 + (m << 5);
      const float* xp = x2b + ((size_t)c << 12) + j0 + jj;
      float v0 = xp[0];
      float v1 = xp[4096];
      float v2 = xp[8192];
      float v3 = xp[12288];
      u32 h0 = pkrtz(v0, v1), h1 = pkrtz(v2, v3);
      float l0 = v0 - h2fu(h0), l1 = v1 - h2fu(h0 >> 16);
      float l2 = v2 - h2fu(h1), l3 = v3 - h2fu(h1 >> 16);
      u32x2 hw; hw.x = h0; hw.y = h1;
      u32x2 lw; lw.x = pkrtz(l0, l1); lw.y = pkrtz(l2, l3);
      *(u32x2*)(Khi + jj * RS + c) = hw;
      *(u32x2*)(Klo + jj * RS + c) = lw;
    }
#pragma unroll
    for (int m = 0; m < 8; ++m) {
      int c = cV + (m << 5);
      float4 v = *(const float4*)(x2b + ((size_t)c << 12) + j0 + (jf << 2));
      u32x2 hw; hw.x = pkrtz(v.x, v.y); hw.y = pkrtz(v.z, v.w);
      *(u32x2*)(V + c * RSV + (jf << 2)) = hw;
    }
    __syncthreads();

    f32x4 aS = {0.f, 0.f, 0.f, 0.f};
#pragma unroll
    for (int cs = 0; cs < 8; ++cs) {
      Frag8 Ah, Al;
      Ah.u4 = *(const u32x4*)(Khi + arow0 + (cs << 5));
      Al.u4 = *(const u32x4*)(Klo + arow0 + (cs << 5));
      aS = MFMA32(Ah.f, QBh[cs].f, aS);
      aS = MFMA32(Ah.f, QBl[cs].f, aS);
      aS = MFMA32(Al.f, QBh[cs].f, aS);
    }

    float4 r2v = *(const float4*)(r2p + j0);
    float s0 = aS[0] + r2v.x, s1 = aS[1] + r2v.y;
    float s2 = aS[2] + r2v.z, s3 = aS[3] + r2v.w;
    float mx = fmaxf(fmaxf(s0, s1), fmaxf(s2, s3));
    mx = fmaxf(mx, __shfl_xor(mx, 16));
    mx = fmaxf(mx, __shfl_xor(mx, 32));
    float mn  = fmaxf(m_run, mx);
    float scl = __expf(m_run - mn);
    float p0 = __expf(s0 - mn), p1 = __expf(s1 - mn);
    float p2 = __expf(s2 - mn), p3 = __expf(s3 - mn);
    float rs = p0 + p1 + p2 + p3;
    rs += __shfl_xor(rs, 16);
    rs += __shfl_xor(rs, 32);
    l_run = l_run * scl + rs;
    m_run = mn;

    Frag4 Pf;
    Pf.u2.x = pkrtz(p0, p1);
    Pf.u2.y = pkrtz(p2, p3);

#pragma unroll
    for (int ct = 0; ct < 16; ++ct) {
      vacc[ct][0] *= scl; vacc[ct][1] *= scl;
      vacc[ct][2] *= scl; vacc[ct][3] *= scl;
    }
#pragma unroll
    for (int ct = 0; ct < 16; ++ct) {
      Frag4 Vf;
      Vf.u2 = *(const u32x2*)(V + (lq + (ct << 4)) * RSV + vcol);
      vacc[ct] = MFMA16(Vf.f, Pf.f, vacc[ct]);
    }
  }

  __syncthreads();
  float* Msm = B_f;
  float* Lsm = B_f + 64;
  if (g == 0) {
    Msm[p * 32 + h * 16 + lq] = m_run;
    Lsm[p * 32 + h * 16 + lq] = l_run;
  }
  __syncthreads();
  float mo  = Msm[p * 32 + (1 - h) * 16 + lq];
  float lo2 = Lsm[p * 32 + (1 - h) * 16 + lq];
  float mt    = fmaxf(m_run, mo);
  float aSelf = __expf(m_run - mt);
  float l_tot = l_run * aSelf + lo2 * __expf(mo - mt);

  float* Cmb = A_f;
  if (h == 0) {
    float* cb_ = Cmb + p * (CC * RSC);
#pragma unroll
    for (int ct = 0; ct < 16; ++ct)
#pragma unroll
      for (int r = 0; r < 4; ++r)
        cb_[((ct << 4) + (g << 2) + r) * RSC + lq] = vacc[ct][r] * aSelf;
  }
  __syncthreads();
  if (h == 1) {
    const float* cb_ = Cmb + p * (CC * RSC);
    float inv = 1.f / l_tot;
    float* ob = out + ((size_t)b << 20) + i0 + (p << 4) + lq;
#pragma unroll
    for (int ct = 0; ct < 16; ++ct)
#pragma unroll
      for (int r = 0; r < 4; ++r) {
        int c = (ct << 4) + (g << 2) + r;
        ob[(size_t)c << 12] = (vacc[ct][r] * aSelf + cb_[c * RSC + lq]) * inv;
      }
  }
}

extern "C" void kernel_launch(void* const* d_in, const int* in_sizes, int n_in,
                              void* d_out, int out_size, void* d_ws, size_t ws_size,
                              hipStream_t stream) {
  const float* x1 = (const float*)d_in[0];
  const float* x2 = (const float*)d_in[1];
  const float* w1 = (const float*)d_in[2];
  const float* b1 = (const float*)d_in[3];
  const float* w2 = (const float*)d_in[4];
  // b2 (d_in[5]) contributes only row-constant energy terms -> cancels in softmax.

  float* M  = (float*)d_ws;            // 256KB
  float* g  = M + 65536;
  float* r2 = g + 256;                 // 64KB
  float* outp = (float*)d_out;

  const size_t need = (size_t)(65536 + 256 + 16384) * 4 + 2ull * 8388608;

  k_prep<<<CC, 256, 0, stream>>>(w1, w2, b1, M, g);
  k_r2<<<BB * NN / 256, 256, 0, stream>>>(x2, g, r2);

  if (ws_size >= need) {
    ush* kimg = (ush*)(r2 + 16384);    // 8MB
    ush* vimg = kimg + 4194304;        // 8MB
    const int LDS_BYTES = 66048;
    (void)hipFuncSetAttribute((const void*)k_attn,
                              hipFuncAttributeMaxDynamicSharedMemorySize, LDS_BYTES);
    k_cvt<<<BB * (NN / 32), 256, 0, stream>>>(x2, kimg, vimg);
    k_attn<<<BB * (NN / 32), 256, LDS_BYTES, stream>>>(x1, kimg, vimg, M, r2, outp);
  } else {
    const int LDS_BYTES = 74752;
    (void)hipFuncSetAttribute((const void*)k_attn_fb,
                              hipFuncAttributeMaxDynamicSharedMemorySize, LDS_BYTES);
    k_attn_fb<<<BB * (NN / 32), 256, LDS_BYTES, stream>>>(x1, x2, M, r2, outp);
  }
  (void)in_sizes; (void)n_in; (void)out_size; (void)ws_size;
}